// Round 8
// baseline (147.866 us; speedup 1.0000x reference)
//
#include <hip/hip_runtime.h>
#include <hip/hip_bf16.h>

// Z[b,w,t] = sum_c Q[b,w,c] * (K[b,w+t,c] + bias[c,t])
// B=16, T=1024, C=128, K has 2T-1=2047 rows.
//
// Round 10 = round-7 kernel, re-submitted verbatim (three broker timeouts;
// never benched). v7: store-robust counted vmcnt. vmcnt mixes loads+stores;
// if stores can retire OOO vs loads, v6's "vmcnt(6) drains the 4 oldest"
// was unsound. Rule: allow only #loads-issued-this-step outstanding. Queue
// = 4 old loads + 2 stores + 4 new loads; vmcnt(4) => >=6 retired, <=2 of
// them stores => all 4 old loads retired, for ANY store order (assumes only
// that loads retire in-order among loads, m135). Sound under BOTH the
// in-order and OOO-store retirement models. s=0 edge: prologue staged loads
// already retired (compiler waited on younger Q loads; in-order load
// retirement). Tail uses vmcnt(0). sched_barrier(0) after barriers (rule
// #18). Plus v6's fixes: no in-loop store drain; coalesced 2x dwordx4
// epilogue via Bss (full 128B lines -> kills partial-line RMW traffic).

#define B_    16
#define T_    1024
#define C_    128
#define KT_   2047

// fallback tile params (round-1 kernel)
#define BW    32
#define BT    64
#define KROWS 96
#define SS_LD 98
#define LDB   136

#define LDSS  130   // Ss leading dim; diag read stride 131 == 3 mod 32 -> 2-way (free)
#define LDBS  65    // Bss leading dim; read stride 65 == 1 mod 32 -> 2-way (free)

typedef unsigned short ushort_t;
typedef short bf16x8 __attribute__((ext_vector_type(8)));
typedef float f32x4  __attribute__((ext_vector_type(4)));

__device__ __forceinline__ unsigned short f2bf(float f) {
  unsigned int u = __float_as_uint(f);
  u += 0x7FFFu + ((u >> 16) & 1u);
  return (unsigned short)(u >> 16);
}

__device__ __forceinline__ bf16x8 pack8(float4 lo, float4 hi) {
  bf16x8 r;
  r[0] = (short)f2bf(lo.x); r[1] = (short)f2bf(lo.y);
  r[2] = (short)f2bf(lo.z); r[3] = (short)f2bf(lo.w);
  r[4] = (short)f2bf(hi.x); r[5] = (short)f2bf(hi.y);
  r[6] = (short)f2bf(hi.z); r[7] = (short)f2bf(hi.w);
  return r;
}

typedef const __attribute__((address_space(1))) unsigned int* gas_ptr;
typedef __attribute__((address_space(3))) unsigned int* las_ptr;
__device__ __forceinline__ void async_copy16(const void* g, void* l) {
  __builtin_amdgcn_global_load_lds((gas_ptr)g, (las_ptr)l, 16, 0, 0);
}

// swizzled fragment pointer: chunk kc (8 bf16) of LDS row `row` (128 bf16/row)
__device__ __forceinline__ const bf16x8* frag(const ushort_t* t, int row, int kc) {
  return (const bf16x8*)(t + (((row << 4) + (kc ^ (row & 7))) << 3));
}

// ---------------- pre-pass: K f32->bf16, bias f32->bf16 transposed ----------------
#define KN4 1048064   // 16*2047*128/4
#define BN4 32768     // 128*1024/4

__global__ __launch_bounds__(256) void prepass(
    const float* __restrict__ K, const float* __restrict__ bias,
    ushort_t* __restrict__ Kb, ushort_t* __restrict__ bT) {
  int idx = blockIdx.x * 256 + threadIdx.x;
  if (idx < KN4) {
    float4 v = ((const float4*)K)[idx];
    ((ushort4*)Kb)[idx] = make_ushort4(f2bf(v.x), f2bf(v.y), f2bf(v.z), f2bf(v.w));
  } else {
    int i = idx - KN4;        // < BN4 (grid sized exactly)
    int c = i >> 8;           // 0..127
    int g = i & 255;          // group of 4 along t
    float4 v = ((const float4*)(bias + c * T_))[g];
    int t = g << 2;
    bT[(t + 0) * C_ + c] = f2bf(v.x);
    bT[(t + 1) * C_ + c] = f2bf(v.y);
    bT[(t + 2) * C_ + c] = f2bf(v.z);
    bT[(t + 3) * C_ + c] = f2bf(v.w);
  }
}

// ---------------- main kernel (persistent over t0) ----------------
// LDS rows of 128 bf16 (16 chunks of 16B), XOR-swizzled:
//   rows   0..191 : K ring, 3 slots x 64 rows (slot p at row 64p)
//   rows 192..319 : bias^T, 2 bufs x 64 rows (buf q at row 192+64q)
// Ss : f32 [64][LDSS] band scratch.  Bss : f32 [64][LDBS] bias-GEMM scratch.
__global__ __launch_bounds__(512) void swmm_main(
    const float* __restrict__ Q, const ushort_t* __restrict__ Kb,
    const ushort_t* __restrict__ bT, float* __restrict__ out) {
  __shared__ __align__(16) ushort_t tile[5120 * 8];   // 80 KB
  __shared__ __align__(16) float Ss[64 * LDSS];       // 33.3 KB
  __shared__ __align__(16) float Bss[64 * LDBS];      // 16.6 KB  (total 128.8 KB)

  const int b    = blockIdx.x;
  const int w0   = blockIdx.y * 64;
  const int tid  = threadIdx.x;
  const int wv   = tid >> 6;
  const int lane = tid & 63;
  const int frow = lane & 15;
  const int quad = lane >> 4;
  const int jb   = wv & 3;          // this wave's bias 16-col block
  const int mg   = wv >> 2;         // this wave's bias m-pair {32mg, 32mg+16}

  // staging per-thread constants (pre-swizzled global source, linear LDS dest)
  const int r0 = tid >> 4;                  // 0..31
  const int cc = (tid & 15) ^ (r0 & 7);     // source chunk, XOR pre-applied
  const ushort_t* kbb = Kb + (size_t)b * KT_ * C_ + (cc << 3);
  const ushort_t* btb = bT + (cc << 3);

  auto stageK = [&](int chunk, int p) {
    int g0 = w0 + chunk * 64 + r0;          // <= 2015, always in range
    int g1 = g0 + 32;
    if (g1 > KT_ - 1) g1 = KT_ - 1;         // chunk-16 tail row: unused, clamp addr
    async_copy16(kbb + (size_t)g0 * C_, &tile[(size_t)(p * 1024 + wv * 64) * 8]);
    async_copy16(kbb + (size_t)g1 * C_, &tile[(size_t)(p * 1024 + 512 + wv * 64) * 8]);
  };
  auto stageB = [&](int step, int q) {
    const ushort_t* g = btb + (size_t)(step * 64 + r0) * C_;
    async_copy16(g,           &tile[(size_t)(3072 + q * 1024 + wv * 64) * 8]);
    async_copy16(g + 32 * C_, &tile[(size_t)(3072 + q * 1024 + 512 + wv * 64) * 8]);
  };

  // ---- prologue: stage chunk0, chunk1, bias0 (6 vmem); then Q loads ----
  stageK(0, 0); stageK(1, 1); stageB(0, 0);

  bf16x8 a[4][4];   // [m-tile][kk]
  {
    const float* qp = Q + ((size_t)(b * T_ + w0 + frow) << 7);
#pragma unroll
    for (int mi = 0; mi < 4; ++mi) {
      const float* qm = qp + ((size_t)(mi * 16) << 7);
#pragma unroll
      for (int kk = 0; kk < 4; ++kk) {
        int co = (kk * 4 + quad) << 3;
        float4 lo = *(const float4*)(qm + co);
        float4 hi = *(const float4*)(qm + co + 4);
        a[mi][kk] = pack8(lo, hi);   // compiler inserts its own vmcnt for Q here
      }
    }
  }

  // passB per-thread constants
  const int pi_row = tid >> 3;              // 0..63
  const int pj0    = (tid & 7) * 8;         // 0,8,..,56
  float* outb = out + ((size_t)(b * T_ + w0 + pi_row) * T_) + pj0;

  int p0 = 0, p1 = 1, p2 = 2;   // ring slots holding chunks s, s+1, s+2

  for (int s = 0; s < 16; ++s) {
    const int q0 = s & 1;

    // ---- top: issue prefetch for s+1 (4 loads) ----
    if (s < 15) {
      stageK(s + 2, p2);          // chunk s+2, consumed from step s+1
      stageB(s + 1, q0 ^ 1);      // bias tile s+1
    }
    // Store-robust counted wait. Loads retire in-order among loads; stores
    // may retire OOO vs loads. Queue here: [4 old loads, 2 stores, 4 new
    // loads]. vmcnt(4) => >=6 retired, of which <=2 are stores => all 4
    // old loads (this step's staged data) retired -- for ANY store timing.
    // Tail (s==15): no new loads issued -> full drain.
    if (s < 15) asm volatile("s_waitcnt vmcnt(4)" ::: "memory");
    else        asm volatile("s_waitcnt vmcnt(0)" ::: "memory");
    __builtin_amdgcn_s_barrier();            // staged LDS visible to all waves
    __builtin_amdgcn_sched_barrier(0);

    // ---- compute ----
    __builtin_amdgcn_s_setprio(1);
    // band: column tile n0 = 16*wv, all 4 m-tiles share each B-frag
    {
      const int n0 = wv * 16;                           // 0..112
      const int pc = (wv >= 4) ? p1 : p0;
      const int lrow = pc * 64 + ((n0 + frow) & 63);
      f32x4 acc[4];
#pragma unroll
      for (int mi = 0; mi < 4; ++mi) acc[mi] = (f32x4){0.f, 0.f, 0.f, 0.f};
#pragma unroll
      for (int kk = 0; kk < 4; ++kk) {
        bf16x8 bb = *frag(tile, lrow, kk * 4 + quad);   // 1 read -> 4 MFMA
#pragma unroll
        for (int mi = 0; mi < 4; ++mi)
          acc[mi] = __builtin_amdgcn_mfma_f32_16x16x32_bf16(a[mi][kk], bb, acc[mi], 0, 0, 0);
      }
#pragma unroll
      for (int mi = 0; mi < 4; ++mi)
#pragma unroll
        for (int r = 0; r < 4; ++r)
          Ss[(mi * 16 + quad * 4 + r) * LDSS + n0 + frow] = acc[mi][r];
    }
    // bias GEMM: j-tile jb, m-pair {2mg, 2mg+1}; results straight to Bss
    {
      const int brow = 192 + q0 * 64 + jb * 16 + frow;
      f32x4 xA = {0.f, 0.f, 0.f, 0.f};
      f32x4 xB = {0.f, 0.f, 0.f, 0.f};
#pragma unroll
      for (int kk = 0; kk < 4; ++kk) {
        bf16x8 bb = *frag(tile, brow, kk * 4 + quad);
        xA = __builtin_amdgcn_mfma_f32_16x16x32_bf16(a[2 * mg + 0][kk], bb, xA, 0, 0, 0);
        xB = __builtin_amdgcn_mfma_f32_16x16x32_bf16(a[2 * mg + 1][kk], bb, xB, 0, 0, 0);
      }
#pragma unroll
      for (int r = 0; r < 4; ++r) {
        Bss[((2 * mg + 0) * 16 + quad * 4 + r) * LDBS + jb * 16 + frow] = xA[r];
        Bss[((2 * mg + 1) * 16 + quad * 4 + r) * LDBS + jb * 16 + frow] = xB[r];
      }
    }
    __builtin_amdgcn_s_setprio(0);

    asm volatile("s_waitcnt lgkmcnt(0)" ::: "memory");   // Ss/Bss writes + frag reads done
    __builtin_amdgcn_s_barrier();
    __builtin_amdgcn_sched_barrier(0);

    // ---- passB: coalesced epilogue. thread -> row pi_row, cols pj0..pj0+7 ----
    {
      float v[8];
      const float* srow = &Ss[pi_row * LDSS + pi_row + pj0];   // stride-131 diag base
      const float* brow2 = &Bss[pi_row * LDBS + pj0];
#pragma unroll
      for (int k = 0; k < 8; ++k) v[k] = srow[k] + brow2[k];
      float4* dst = (float4*)(outb + (size_t)s * 64);
      dst[0] = make_float4(v[0], v[1], v[2], v[3]);   // 2 dwordx4: 32B/lane,
      dst[1] = make_float4(v[4], v[5], v[6], v[7]);   // wave = full 128B lines
    }
    asm volatile("s_waitcnt lgkmcnt(0)" ::: "memory");   // passB LDS reads done
    // next iteration's top barrier orders these reads vs. step s+1 overwrites

    const int tp = p0; p0 = p1; p1 = p2; p2 = tp;
  }
}

// ---------------- fallback (round-1 kernel) if ws too small ----------------
__global__ __launch_bounds__(256) void swmm_fallback(
    const float* __restrict__ Q, const float* __restrict__ K,
    const float* __restrict__ bias, float* __restrict__ out) {
  __shared__ __align__(16) unsigned short Qs[BW * LDB];
  __shared__ __align__(16) unsigned short Ks[KROWS * LDB];
  __shared__ __align__(16) unsigned short Bs[BT * LDB];
  __shared__ __align__(16) float Ssf[BW * SS_LD];

  const int b   = blockIdx.z;
  const int w0  = blockIdx.y * BW;
  const int t0  = blockIdx.x * BT;
  const int kbase = w0 + t0;
  const int tid = threadIdx.x;

  {
    const float4* src = (const float4*)(Q + (size_t)(b * T_ + w0) * C_);
    for (int v = tid; v < BW * (C_ / 4); v += 256) {
      int r = v >> 5, cc = v & 31;
      float4 q = src[r * 32 + cc];
      unsigned short* d = &Qs[r * LDB + (cc << 2)];
      d[0] = f2bf(q.x); d[1] = f2bf(q.y); d[2] = f2bf(q.z); d[3] = f2bf(q.w);
    }
  }
  {
    for (int v = tid; v < KROWS * (C_ / 4); v += 256) {
      int r = v >> 5, cc = v & 31;
      int g = kbase + r;
      float4 kv = make_float4(0.f, 0.f, 0.f, 0.f);
      if (g < KT_) kv = ((const float4*)(K + ((size_t)b * KT_ + g) * C_))[cc];
      unsigned short* d = &Ks[r * LDB + (cc << 2)];
      d[0] = f2bf(kv.x); d[1] = f2bf(kv.y); d[2] = f2bf(kv.z); d[3] = f2bf(kv.w);
    }
  }
  {
    for (int v = tid; v < C_ * (BT / 4); v += 256) {
      int c = v >> 4, jj = v & 15;
      float4 bv = ((const float4*)(bias + (size_t)c * T_ + t0))[jj];
      int j4 = jj << 2;
      Bs[(j4 + 0) * LDB + c] = f2bf(bv.x);
      Bs[(j4 + 1) * LDB + c] = f2bf(bv.y);
      Bs[(j4 + 2) * LDB + c] = f2bf(bv.z);
      Bs[(j4 + 3) * LDB + c] = f2bf(bv.w);
    }
  }
  __syncthreads();

  const int wv    = tid >> 6;
  const int lane  = tid & 63;
  const int frow  = lane & 15;
  const int koff  = (lane >> 4) * 8;
  const int drow4 = (lane >> 4) * 4;
  const int NS = KROWS / 16;

  for (int s = wv; s < 2 * NS; s += 4) {
    int mb = s / NS, nn = s % NS;
    int m0 = mb * 16, n0 = nn * 16;
    const unsigned short* arow = &Qs[(m0 + frow) * LDB + koff];
    const unsigned short* brow = &Ks[(n0 + frow) * LDB + koff];
    f32x4 acc = {0.f, 0.f, 0.f, 0.f};
#pragma unroll
    for (int k0 = 0; k0 < C_; k0 += 32) {
      bf16x8 a  = *(const bf16x8*)(arow + k0);
      bf16x8 bb = *(const bf16x8*)(brow + k0);
      acc = __builtin_amdgcn_mfma_f32_16x16x32_bf16(a, bb, acc, 0, 0, 0);
    }
#pragma unroll
    for (int r = 0; r < 4; ++r)
      Ssf[(m0 + drow4 + r) * SS_LD + n0 + frow] = acc[r];
  }

  f32x4 bacc[2];
#pragma unroll
  for (int q = 0; q < 2; ++q) {
    int idx = wv + q * 4;
    int m0 = (idx >> 2) * 16, jj0 = (idx & 3) * 16;
    const unsigned short* arow = &Qs[(m0 + frow) * LDB + koff];
    const unsigned short* brow = &Bs[(jj0 + frow) * LDB + koff];
    f32x4 acc = {0.f, 0.f, 0.f, 0.f};
#pragma unroll
    for (int k0 = 0; k0 < C_; k0 += 32) {
      bf16x8 a  = *(const bf16x8*)(arow + k0);
      bf16x8 bb = *(const bf16x8*)(brow + k0);
      acc = __builtin_amdgcn_mfma_f32_16x16x32_bf16(a, bb, acc, 0, 0, 0);
    }
    bacc[q] = acc;
  }
  __syncthreads();

#pragma unroll
  for (int q = 0; q < 2; ++q) {
    int idx = wv + q * 4;
    int m0 = (idx >> 2) * 16, jj0 = (idx & 3) * 16;
#pragma unroll
    for (int r = 0; r < 4; ++r) {
      int i = m0 + drow4 + r;
      int j = jj0 + frow;
      out[(size_t)(b * T_ + w0 + i) * T_ + t0 + j] = bacc[q][r] + Ssf[i * SS_LD + i + j];
    }
  }
}

extern "C" void kernel_launch(void* const* d_in, const int* in_sizes, int n_in,
                              void* d_out, int out_size, void* d_ws, size_t ws_size,
                              hipStream_t stream) {
  const float* Q    = (const float*)d_in[0];
  const float* K    = (const float*)d_in[1];
  const float* bias = (const float*)d_in[2];
  float* out = (float*)d_out;

  const size_t KB = (size_t)B_ * KT_ * C_ * 2;       // 8.38 MB
  const size_t TB = (size_t)T_ * C_ * 2;             // 0.25 MB

  if (ws_size >= KB + TB) {
    ushort_t* Kb = (ushort_t*)d_ws;
    ushort_t* bT = (ushort_t*)((char*)d_ws + KB);
    prepass<<<(KN4 + BN4) / 256, 256, 0, stream>>>(K, bias, Kb, bT);
    // grid x = b so XCD round-robin (id%8) groups blocks by b -> K reuse in per-XCD L2
    swmm_main<<<dim3(B_, T_ / 64), dim3(512), 0, stream>>>(Q, Kb, bT, out);
  } else {
    swmm_fallback<<<dim3(T_ / BT, T_ / BW, B_), dim3(256), 0, stream>>>(Q, K, bias, out);
  }
}

// Round 10
// 123.043 us; speedup vs baseline: 1.2017x; 1.2017x over previous
//
#include <hip/hip_runtime.h>
#include <hip/hip_bf16.h>

// Z[b,w,t] = sum_c Q[b,w,c] * (K[b,w+t,c] + bias[c,t])
// B=16, T=1024, C=128, K has 2T-1=2047 rows.
//
// Round 12 = round-11 kernel resubmitted verbatim (broker timeout; never
// benched). One-shot architecture (v4: 8192 blocks, 256 thr, 48 KB LDS ->
// 3 blocks/CU). Post-mortem of v5/v7: persistent 1-block/CU designs
// measured 52-72us with all pipes <10% busy -- no co-resident block to
// hide staging latency/barrier skew (Guideline 1). v4 measured <43us
// (absent from top-5). Single fix on top of v4: the scattered 4B epilogue
// stores (partial-line RMW -> 96MB writes) replaced by Bss LDS
// redistribution (overlaid on the dead K region, +1 barrier) +
// 8-contiguous-float stores per thread (full 128B lines per wave).

#define B_    16
#define T_    1024
#define C_    128
#define KT_   2047

#define BW    32
#define BT    64
#define KROWS 96
#define SS_LD 98
#define LDBS2 68    // Bss leading dim (floats): writes 2-way, b128 reads aligned

typedef unsigned short ushort_t;
typedef short bf16x8 __attribute__((ext_vector_type(8)));
typedef float f32x4  __attribute__((ext_vector_type(4)));

__device__ __forceinline__ unsigned short f2bf(float f) {
  unsigned int u = __float_as_uint(f);
  u += 0x7FFFu + ((u >> 16) & 1u);
  return (unsigned short)(u >> 16);
}

typedef const __attribute__((address_space(1))) unsigned int* gas_ptr;
typedef __attribute__((address_space(3))) unsigned int* las_ptr;
__device__ __forceinline__ void async_copy16(const void* g, void* l) {
  __builtin_amdgcn_global_load_lds((gas_ptr)g, (las_ptr)l, 16, 0, 0);
}

// swizzled fragment pointer: chunk kc (8 bf16) of LDS row `row`
__device__ __forceinline__ const bf16x8* frag(const ushort_t* t, int row, int kc) {
  return (const bf16x8*)(t + (((row << 4) + (kc ^ (row & 7))) << 3));
}

// ---------------- pre-pass: f32 -> bf16 (+ bias transpose) ----------------
#define QN4 524288    // 16*1024*128/4
#define KN4 1048064   // 16*2047*128/4
#define BN4 32768     // 128*1024/4

__global__ __launch_bounds__(256) void prepass(
    const float* __restrict__ Q, const float* __restrict__ K,
    const float* __restrict__ bias, ushort_t* __restrict__ Qb,
    ushort_t* __restrict__ Kb, ushort_t* __restrict__ bT) {
  int idx = blockIdx.x * 256 + threadIdx.x;
  if (idx < QN4) {
    float4 v = ((const float4*)Q)[idx];
    ((ushort4*)Qb)[idx] = make_ushort4(f2bf(v.x), f2bf(v.y), f2bf(v.z), f2bf(v.w));
  } else if (idx < QN4 + KN4) {
    int i = idx - QN4;
    float4 v = ((const float4*)K)[i];
    ((ushort4*)Kb)[i] = make_ushort4(f2bf(v.x), f2bf(v.y), f2bf(v.z), f2bf(v.w));
  } else if (idx < QN4 + KN4 + BN4) {
    int i = idx - (QN4 + KN4);
    int c = i >> 8;           // 0..127
    int g = i & 255;          // group of 4 along t
    float4 v = ((const float4*)(bias + c * T_))[g];
    int t = g << 2;
    bT[(t + 0) * C_ + c] = f2bf(v.x);
    bT[(t + 1) * C_ + c] = f2bf(v.y);
    bT[(t + 2) * C_ + c] = f2bf(v.z);
    bT[(t + 3) * C_ + c] = f2bf(v.w);
  }
}

// ---------------- main kernel (one-shot, 3 blocks/CU) ----------------
// LDS rows (swizzled, 128 bf16 = 16 chunks each):
//   rows 0..31   : Q tile
//   rows 32..127 : K band (96 rows)     (overlaid by Bss in phase 3)
//   rows 128..191: bias^T tile          (overlaid by f32 Ss after phase 1)
__global__ __launch_bounds__(256) void swmm_main(
    const ushort_t* __restrict__ Qb, const ushort_t* __restrict__ Kb,
    const ushort_t* __restrict__ bT, float* __restrict__ out) {
  __shared__ __align__(16) ushort_t tile[3072 * 8];   // 48 KB

  const int b  = blockIdx.z;
  const int w0 = blockIdx.y * BW;
  const int t0 = blockIdx.x * BT;
  const int kbase = w0 + t0;
  const int tid = threadIdx.x;
  const int wv = tid >> 6, lane = tid & 63;

  // ---- stage: 3072 slots of 16B, 12 segments of 256 ----
#pragma unroll
  for (int seg = 0; seg < 12; ++seg) {
    int slot = seg * 256 + tid;
    int r = slot >> 4;                      // LDS row 0..191
    int c = (slot & 15) ^ (r & 7);          // source chunk (XOR swizzle)
    const ushort_t* g;
    if (seg < 2) {
      g = Qb + (((size_t)(b * T_ + w0 + r)) << 7) + (c << 3);
    } else if (seg < 8) {
      int gk = kbase + (r - 32);
      if (gk > KT_ - 1) gk = KT_ - 1;       // S col 95 is never consumed; clamp addr
      g = Kb + ((size_t)b * KT_ + gk) * C_ + (c << 3);
    } else {
      g = bT + (((size_t)(t0 + r - 128)) << 7) + (c << 3);
    }
    async_copy16(g, &tile[(size_t)(seg * 256 + wv * 64) * 8]);
  }
  __syncthreads();

  const int frow = lane & 15;
  const int quad = lane >> 4;
  const int drow4 = quad * 4;

  // ---- phase 1: bias GEMM, 8 tiles (2 per wave), kept in regs ----
  f32x4 bacc[2];
#pragma unroll
  for (int q = 0; q < 2; ++q) {
    int idx = wv + q * 4;
    int m0 = (idx >> 2) * 16, j0 = (idx & 3) * 16;
    f32x4 acc = {0.f, 0.f, 0.f, 0.f};
#pragma unroll
    for (int kk = 0; kk < 4; ++kk) {
      int kc = kk * 4 + quad;
      bf16x8 a  = *frag(tile, m0 + frow, kc);
      bf16x8 bb = *frag(tile, 128 + j0 + frow, kc);
      acc = __builtin_amdgcn_mfma_f32_16x16x32_bf16(a, bb, acc, 0, 0, 0);
    }
    bacc[q] = acc;
  }
  __syncthreads();   // all waves done reading bias region

  // ---- phase 2: S band tiles (12, 3 per wave) -> f32 Ss overlaid on bias ----
  float* Ss = (float*)&tile[2048 * 8];
#pragma unroll
  for (int q = 0; q < 3; ++q) {
    int s = wv + q * 4;                     // 0..11
    int mb = s / 6, nn = s % 6;
    int m0 = mb * 16, n0 = nn * 16;
    f32x4 acc = {0.f, 0.f, 0.f, 0.f};
#pragma unroll
    for (int kk = 0; kk < 4; ++kk) {
      int kc = kk * 4 + quad;
      bf16x8 a  = *frag(tile, m0 + frow, kc);
      bf16x8 bb = *frag(tile, 32 + n0 + frow, kc);
      acc = __builtin_amdgcn_mfma_f32_16x16x32_bf16(a, bb, acc, 0, 0, 0);
    }
#pragma unroll
    for (int r = 0; r < 4; ++r)
      Ss[(m0 + drow4 + r) * SS_LD + n0 + frow] = acc[r];
  }
  __syncthreads();   // Ss complete; K region now dead

  // ---- phase 3: redistribute bias accs through LDS (overlay dead K region) ----
  // Bss write banks: (68*(m0+4q+r) + j0 + frow) mod 32 -> 2-way only (free).
  float* Bss = (float*)&tile[4096];         // byte 8192, K rows 32..65 (dead)
#pragma unroll
  for (int q = 0; q < 2; ++q) {
    int idx = wv + q * 4;
    int m0 = (idx >> 2) * 16, j0 = (idx & 3) * 16;
#pragma unroll
    for (int r = 0; r < 4; ++r)
      Bss[(m0 + drow4 + r) * LDBS2 + j0 + frow] = bacc[q][r];
  }
  __syncthreads();

  // ---- epilogue: coalesced. thread -> row pi (0..31), cols pj0..pj0+7 ----
  // wave = 8 rows x 256B contiguous -> full 128B lines. Ss diag reads
  // stride 99 == 3 mod 32 -> 2-way (free). Bss reads: aligned ds_read_b128.
  {
    const int pi  = tid >> 3;
    const int pj0 = (tid & 7) * 8;
    float v[8];
    const float* srow = &Ss[pi * SS_LD + pi + pj0];
    const float* brow = &Bss[pi * LDBS2 + pj0];
#pragma unroll
    for (int k = 0; k < 8; ++k) v[k] = srow[k] + brow[k];
    float4* dst = (float4*)(out + (size_t)(b * T_ + w0 + pi) * T_ + t0 + pj0);
    dst[0] = make_float4(v[0], v[1], v[2], v[3]);
    dst[1] = make_float4(v[4], v[5], v[6], v[7]);
  }
}

// ---------------- fallback (round-1 kernel) if ws too small ----------------
#define LDB 136
__global__ __launch_bounds__(256) void swmm_fallback(
    const float* __restrict__ Q, const float* __restrict__ K,
    const float* __restrict__ bias, float* __restrict__ out) {
  __shared__ __align__(16) unsigned short Qs[BW * LDB];
  __shared__ __align__(16) unsigned short Ks[KROWS * LDB];
  __shared__ __align__(16) unsigned short Bs[BT * LDB];
  __shared__ __align__(16) float Ssf[BW * SS_LD];

  const int b   = blockIdx.z;
  const int w0  = blockIdx.y * BW;
  const int t0  = blockIdx.x * BT;
  const int kbase = w0 + t0;
  const int tid = threadIdx.x;

  {
    const float4* src = (const float4*)(Q + (size_t)(b * T_ + w0) * C_);
    for (int v = tid; v < BW * (C_ / 4); v += 256) {
      int r = v >> 5, cc = v & 31;
      float4 q = src[r * 32 + cc];
      unsigned short* d = &Qs[r * LDB + (cc << 2)];
      d[0] = f2bf(q.x); d[1] = f2bf(q.y); d[2] = f2bf(q.z); d[3] = f2bf(q.w);
    }
  }
  {
    for (int v = tid; v < KROWS * (C_ / 4); v += 256) {
      int r = v >> 5, cc = v & 31;
      int g = kbase + r;
      float4 kv = make_float4(0.f, 0.f, 0.f, 0.f);
      if (g < KT_) kv = ((const float4*)(K + ((size_t)b * KT_ + g) * C_))[cc];
      unsigned short* d = &Ks[r * LDB + (cc << 2)];
      d[0] = f2bf(kv.x); d[1] = f2bf(kv.y); d[2] = f2bf(kv.z); d[3] = f2bf(kv.w);
    }
  }
  {
    for (int v = tid; v < C_ * (BT / 4); v += 256) {
      int c = v >> 4, jj = v & 15;
      float4 bv = ((const float4*)(bias + (size_t)c * T_ + t0))[jj];
      int j4 = jj << 2;
      Bs[(j4 + 0) * LDB + c] = f2bf(bv.x);
      Bs[(j4 + 1) * LDB + c] = f2bf(bv.y);
      Bs[(j4 + 2) * LDB + c] = f2bf(bv.z);
      Bs[(j4 + 3) * LDB + c] = f2bf(bv.w);
    }
  }
  __syncthreads();

  const int wv    = tid >> 6;
  const int lane  = tid & 63;
  const int frow  = lane & 15;
  const int koff  = (lane >> 4) * 8;
  const int drow4 = (lane >> 4) * 4;
  const int NS = KROWS / 16;

  for (int s = wv; s < 2 * NS; s += 4) {
    int mb = s / NS, nn = s % NS;
    int m0 = mb * 16, n0 = nn * 16;
    const unsigned short* arow = &Qs[(m0 + frow) * LDB + koff];
    const unsigned short* brow = &Ks[(n0 + frow) * LDB + koff];
    f32x4 acc = {0.f, 0.f, 0.f, 0.f};
#pragma unroll
    for (int k0 = 0; k0 < C_; k0 += 32) {
      bf16x8 a  = *(const bf16x8*)(arow + k0);
      bf16x8 bb = *(const bf16x8*)(brow + k0);
      acc = __builtin_amdgcn_mfma_f32_16x16x32_bf16(a, bb, acc, 0, 0, 0);
    }
#pragma unroll
    for (int r = 0; r < 4; ++r)
      Ssf[(m0 + drow4 + r) * SS_LD + n0 + frow] = acc[r];
  }

  f32x4 bacc[2];
#pragma unroll
  for (int q = 0; q < 2; ++q) {
    int idx = wv + q * 4;
    int m0 = (idx >> 2) * 16, j0 = (idx & 3) * 16;
    const unsigned short* arow = &Qs[(m0 + frow) * LDB + koff];
    const unsigned short* brow = &Bs[(j0 + frow) * LDB + koff];
    f32x4 acc = {0.f, 0.f, 0.f, 0.f};
#pragma unroll
    for (int k0 = 0; k0 < C_; k0 += 32) {
      bf16x8 a  = *(const bf16x8*)(arow + k0);
      bf16x8 bb = *(const bf16x8*)(brow + k0);
      acc = __builtin_amdgcn_mfma_f32_16x16x32_bf16(a, bb, acc, 0, 0, 0);
    }
    bacc[q] = acc;
  }
  __syncthreads();

#pragma unroll
  for (int q = 0; q < 2; ++q) {
    int idx = wv + q * 4;
    int m0 = (idx >> 2) * 16, j0 = (idx & 3) * 16;
#pragma unroll
    for (int r = 0; r < 4; ++r) {
      int i = m0 + drow4 + r;
      int j = j0 + frow;
      out[(size_t)(b * T_ + w0 + i) * T_ + t0 + j] = bacc[q][r] + Ssf[i * SS_LD + i + j];
    }
  }
}

extern "C" void kernel_launch(void* const* d_in, const int* in_sizes, int n_in,
                              void* d_out, int out_size, void* d_ws, size_t ws_size,
                              hipStream_t stream) {
  const float* Q    = (const float*)d_in[0];
  const float* K    = (const float*)d_in[1];
  const float* bias = (const float*)d_in[2];
  float* out = (float*)d_out;

  const size_t QB = (size_t)B_ * T_ * C_ * 2;        // 4 MB
  const size_t KB = (size_t)B_ * KT_ * C_ * 2;       // 8.38 MB
  const size_t TB = (size_t)T_ * C_ * 2;             // 0.25 MB
  dim3 grid(T_ / BT, T_ / BW, B_);                   // 8192 blocks

  if (ws_size >= QB + KB + TB) {
    ushort_t* Qb = (ushort_t*)d_ws;
    ushort_t* Kb = (ushort_t*)((char*)d_ws + QB);
    ushort_t* bT = (ushort_t*)((char*)d_ws + QB + KB);
    prepass<<<(QN4 + KN4 + BN4) / 256, 256, 0, stream>>>(Q, K, bias, Qb, Kb, bT);
    swmm_main<<<grid, dim3(256), 0, stream>>>(Qb, Kb, bT, out);
  } else {
    swmm_fallback<<<grid, dim3(256), 0, stream>>>(Q, K, bias, out);
  }
}